// Round 1
// baseline (51.276 us; speedup 1.0000x reference)
//
#include <hip/hip_runtime.h>
#include <hip/hip_bf16.h>

typedef short bf16x8 __attribute__((ext_vector_type(8)));
typedef float f32x4  __attribute__((ext_vector_type(4)));

#define NB 64
#define NN 512
#define DD 128

// RNE float -> bf16 (finite inputs)
__device__ __forceinline__ unsigned short f2bf(float f) {
    unsigned int u = __float_as_uint(f);
    unsigned int r = (u + 0x7FFFu + ((u >> 16) & 1u)) >> 16;
    return (unsigned short)r;
}

// Kernel 1: per-row L2 normalize, write bf16 fn into workspace.
// One wave per row (D=128 -> 2 floats/lane). Grid: 32768 rows / 4 waves.
__global__ __launch_bounds__(256) void ASG_norm_kernel(
    const float* __restrict__ fea, unsigned int* __restrict__ fn)
{
    const int wid  = threadIdx.x >> 6;
    const int lane = threadIdx.x & 63;
    const int row  = blockIdx.x * 4 + wid;          // 0..32767
    const float2* src = reinterpret_cast<const float2*>(fea) + (size_t)row * (DD / 2);
    float2 v = src[lane];
    float s = v.x * v.x + v.y * v.y;
#pragma unroll
    for (int o = 32; o; o >>= 1) s += __shfl_xor(s, o);
    float scale = 1.0f / fmaxf(sqrtf(s), 1e-8f);
    unsigned short a = f2bf(v.x * scale);
    unsigned short b = f2bf(v.y * scale);
    fn[(size_t)row * (DD / 2) + lane] = (unsigned int)a | ((unsigned int)b << 16);
}

// Kernel 2: per (batch, 128x128 tile): cos via MFMA on bf16 fn, then
// dist/exp gating epilogue. 4 waves, each owns a 64x64 sub-tile.
__global__ __launch_bounds__(256) void ASG_adj_kernel(
    const unsigned short* __restrict__ fn, const float* __restrict__ coord,
    float* __restrict__ out)
{
    const int b   = blockIdx.z;
    const int bi  = blockIdx.y;       // row tile 0..3
    const int bj  = blockIdx.x;       // col tile 0..3
    const int tid = threadIdx.x;
    const int wid = tid >> 6, lane = tid & 63;
    const int wr  = wid >> 1, wc = wid & 1;
    const int row0 = bi * 128 + wr * 64;
    const int col0 = bj * 128 + wc * 64;

    __shared__ float2 crow[128];
    __shared__ float2 ccol[128];
    const float2* cb = reinterpret_cast<const float2*>(coord) + (size_t)b * NN;
    if (tid < 128) crow[tid] = cb[bi * 128 + tid];
    else           ccol[tid - 128] = cb[bj * 128 + (tid - 128)];
    __syncthreads();

    const unsigned short* fb = fn + (size_t)b * NN * DD;
    const int lrow = lane & 15;        // fragment row/col index
    const int lk   = (lane >> 4) * 8;  // k start (bf16 elements)

    // B fragments: col = col0 + n*16 + lrow, k = kk*32 + lk .. +8
    bf16x8 bfrag[4][4];
#pragma unroll
    for (int n = 0; n < 4; ++n) {
        const unsigned short* p = fb + (size_t)(col0 + n * 16 + lrow) * DD + lk;
#pragma unroll
        for (int kk = 0; kk < 4; ++kk)
            bfrag[n][kk] = *reinterpret_cast<const bf16x8*>(p + kk * 32);
    }

    f32x4 acc[4][4];
#pragma unroll
    for (int m = 0; m < 4; ++m)
#pragma unroll
        for (int n = 0; n < 4; ++n)
            acc[m][n] = (f32x4){0.f, 0.f, 0.f, 0.f};

#pragma unroll
    for (int m = 0; m < 4; ++m) {
        const unsigned short* p = fb + (size_t)(row0 + m * 16 + lrow) * DD + lk;
        bf16x8 afrag[4];
#pragma unroll
        for (int kk = 0; kk < 4; ++kk)
            afrag[kk] = *reinterpret_cast<const bf16x8*>(p + kk * 32);
#pragma unroll
        for (int n = 0; n < 4; ++n)
#pragma unroll
            for (int kk = 0; kk < 4; ++kk)
                acc[m][n] = __builtin_amdgcn_mfma_f32_16x16x32_bf16(
                    afrag[kk], bfrag[n][kk], acc[m][n], 0, 0, 0);
    }

    // Epilogue. C/D layout: col = lane&15, row = (lane>>4)*4 + reg.
    float* outA = out + (size_t)b * NN * NN;
    float* outS = out + (size_t)NB * NN * NN + (size_t)b * NN * NN;
    const int rgrp = (lane >> 4) * 4;

#pragma unroll
    for (int n = 0; n < 4; ++n) {
        const int j = col0 + n * 16 + lrow;
        const float2 cj = ccol[wc * 64 + n * 16 + lrow];
#pragma unroll
        for (int m = 0; m < 4; ++m) {
#pragma unroll
            for (int r = 0; r < 4; ++r) {
                const int i = row0 + m * 16 + rgrp + r;
                const float2 ci = crow[wr * 64 + m * 16 + rgrp + r];
                // bit-exact match to numpy: mul, mul, add, sqrt (no FMA)
                const float dx = ci.x - cj.x;
                const float dy = ci.y - cj.y;
                const float d2 = __fadd_rn(__fmul_rn(dx, dx), __fmul_rn(dy, dy));
                const float dist = __fsqrt_rn(d2);
                const float cosv = acc[m][n][r];
                const bool diag = (i == j);
                const float av = diag ? 0.0f : cosv * __expf(-dist);
                const float sv = (!diag && dist < 1.0f) ? 1.0f : 0.0f;
                const size_t off = (size_t)i * NN + j;
                outA[off] = av;
                outS[off] = sv;
            }
        }
    }
}

extern "C" void kernel_launch(void* const* d_in, const int* in_sizes, int n_in,
                              void* d_out, int out_size, void* d_ws, size_t ws_size,
                              hipStream_t stream) {
    const float* fea   = (const float*)d_in[0];   // [64,512,128] f32
    const float* coord = (const float*)d_in[1];   // [64,512,2]   f32
    float* out = (float*)d_out;                   // [2,64,512,512] f32
    unsigned int* fn_ws = (unsigned int*)d_ws;    // bf16 fn, 8 MB

    ASG_norm_kernel<<<dim3(NB * NN / 4), 256, 0, stream>>>(fea, fn_ws);
    ASG_adj_kernel<<<dim3(4, 4, NB), 256, 0, stream>>>(
        (const unsigned short*)fn_ws, coord, out);
}

// Round 2
// 50.153 us; speedup vs baseline: 1.0224x; 1.0224x over previous
//
#include <hip/hip_runtime.h>
#include <hip/hip_bf16.h>

typedef short bf16x8 __attribute__((ext_vector_type(8)));
typedef float f32x4  __attribute__((ext_vector_type(4)));

#define NB 64
#define NN 512
#define DD 128

// RNE float -> bf16 (finite inputs)
__device__ __forceinline__ unsigned short f2bf(float f) {
    unsigned int u = __float_as_uint(f);
    unsigned int r = (u + 0x7FFFu + ((u >> 16) & 1u)) >> 16;
    return (unsigned short)r;
}

// Kernel 1: per-row L2 normalize, write bf16 fn into workspace.
__global__ __launch_bounds__(256) void ASG_norm_kernel(
    const float* __restrict__ fea, unsigned int* __restrict__ fn)
{
    const int wid  = threadIdx.x >> 6;
    const int lane = threadIdx.x & 63;
    const int row  = blockIdx.x * 4 + wid;          // 0..32767
    const float2* src = reinterpret_cast<const float2*>(fea) + (size_t)row * (DD / 2);
    float2 v = src[lane];
    float s = v.x * v.x + v.y * v.y;
#pragma unroll
    for (int o = 32; o; o >>= 1) s += __shfl_xor(s, o);
    float scale = 1.0f / fmaxf(sqrtf(s), 1e-8f);
    unsigned short a = f2bf(v.x * scale);
    unsigned short b = f2bf(v.y * scale);
    fn[(size_t)row * (DD / 2) + lane] = (unsigned int)a | ((unsigned int)b << 16);
}

// Kernel 2: per (batch, 128x128 tile): cos via MFMA on bf16 fn; epilogue
// transposes each 16x64 acc chunk through wave-private LDS so stores are
// dwordx4 covering 256B-contiguous runs (full L2 lines).
__global__ __launch_bounds__(256) void ASG_adj_kernel(
    const unsigned short* __restrict__ fn, const float* __restrict__ coord,
    float* __restrict__ out)
{
    const int b   = blockIdx.z;
    const int bi  = blockIdx.y;       // row tile 0..3
    const int bj  = blockIdx.x;       // col tile 0..3
    const int tid = threadIdx.x;
    const int wid = tid >> 6, lane = tid & 63;
    const int wr  = wid >> 1, wc = wid & 1;
    const int row0 = bi * 128 + wr * 64;
    const int col0 = bj * 128 + wc * 64;
    const int lo = lane & 15, hi = lane >> 4;

    __shared__ float2 crow[128];
    __shared__ float2 ccol[128];
    __shared__ float  xpose[4][16 * 68];   // per-wave transpose buffer (pad 68)

    const float2* cb = reinterpret_cast<const float2*>(coord) + (size_t)b * NN;
    if (tid < 128) crow[tid] = cb[bi * 128 + tid];
    else           ccol[tid - 128] = cb[bj * 128 + (tid - 128)];
    __syncthreads();

    const unsigned short* fb = fn + (size_t)b * NN * DD;
    const int lk = hi * 8;             // k start (bf16 elements)

    // B fragments: col = col0 + n*16 + lo, k = kk*32 + lk .. +8
    bf16x8 bfrag[4][4];
#pragma unroll
    for (int n = 0; n < 4; ++n) {
        const unsigned short* p = fb + (size_t)(col0 + n * 16 + lo) * DD + lk;
#pragma unroll
        for (int kk = 0; kk < 4; ++kk)
            bfrag[n][kk] = *reinterpret_cast<const bf16x8*>(p + kk * 32);
    }

    f32x4 acc[4][4];
#pragma unroll
    for (int m = 0; m < 4; ++m)
#pragma unroll
        for (int n = 0; n < 4; ++n)
            acc[m][n] = (f32x4){0.f, 0.f, 0.f, 0.f};

#pragma unroll
    for (int m = 0; m < 4; ++m) {
        const unsigned short* p = fb + (size_t)(row0 + m * 16 + lo) * DD + lk;
        bf16x8 afrag[4];
#pragma unroll
        for (int kk = 0; kk < 4; ++kk)
            afrag[kk] = *reinterpret_cast<const bf16x8*>(p + kk * 32);
#pragma unroll
        for (int n = 0; n < 4; ++n)
#pragma unroll
            for (int kk = 0; kk < 4; ++kk)
                acc[m][n] = __builtin_amdgcn_mfma_f32_16x16x32_bf16(
                    afrag[kk], bfrag[n][kk], acc[m][n], 0, 0, 0);
    }

    // Epilogue. MFMA C layout: local col = lo, local row = hi*4 + r.
    float* outA = out + (size_t)b * NN * NN;
    float* outS = out + (size_t)NB * NN * NN + (size_t)b * NN * NN;
    float* xp = xpose[wid];

    // this lane's 4 output columns (after transpose)
    const int jbase = col0 + lo * 4;
    float2 cj[4];
#pragma unroll
    for (int q = 0; q < 4; ++q) cj[q] = ccol[wc * 64 + lo * 4 + q];

#pragma unroll
    for (int m = 0; m < 4; ++m) {
        // scatter acc[m][*] into LDS: [local_row][local_col], stride 68
#pragma unroll
        for (int n = 0; n < 4; ++n)
#pragma unroll
            for (int r = 0; r < 4; ++r)
                xp[(hi * 4 + r) * 68 + n * 16 + lo] = acc[m][n][r];
        // read back transposed: 4 rows x 64 cols per pass, dwordx4/lane
#pragma unroll
        for (int p = 0; p < 4; ++p) {
            const int rr = p * 4 + hi;                 // local row 0..15
            const f32x4 cv = *reinterpret_cast<const f32x4*>(&xp[rr * 68 + lo * 4]);
            const int i = row0 + m * 16 + rr;
            const float2 ci = crow[wr * 64 + m * 16 + rr];
            f32x4 av, sv;
#pragma unroll
            for (int q = 0; q < 4; ++q) {
                const int j = jbase + q;
                // bit-exact match to numpy: mul, mul, add, sqrt (no FMA)
                const float dx = ci.x - cj[q].x;
                const float dy = ci.y - cj[q].y;
                const float d2 = __fadd_rn(__fmul_rn(dx, dx), __fmul_rn(dy, dy));
                const float dist = __fsqrt_rn(d2);
                const bool diag = (i == j);
                av[q] = diag ? 0.0f : cv[q] * __expf(-dist);
                sv[q] = (!diag && dist < 1.0f) ? 1.0f : 0.0f;
            }
            const size_t off = (size_t)i * NN + jbase;
            __builtin_nontemporal_store(av, reinterpret_cast<f32x4*>(outA + off));
            __builtin_nontemporal_store(sv, reinterpret_cast<f32x4*>(outS + off));
        }
    }
}

extern "C" void kernel_launch(void* const* d_in, const int* in_sizes, int n_in,
                              void* d_out, int out_size, void* d_ws, size_t ws_size,
                              hipStream_t stream) {
    const float* fea   = (const float*)d_in[0];   // [64,512,128] f32
    const float* coord = (const float*)d_in[1];   // [64,512,2]   f32
    float* out = (float*)d_out;                   // [2,64,512,512] f32
    unsigned int* fn_ws = (unsigned int*)d_ws;    // bf16 fn, 8 MB

    ASG_norm_kernel<<<dim3(NB * NN / 4), 256, 0, stream>>>(fea, fn_ws);
    ASG_adj_kernel<<<dim3(4, 4, NB), 256, 0, stream>>>(
        (const unsigned short*)fn_ws, coord, out);
}

// Round 3
// 44.472 us; speedup vs baseline: 1.1530x; 1.1278x over previous
//
#include <hip/hip_runtime.h>
#include <hip/hip_bf16.h>

typedef short bf16x8 __attribute__((ext_vector_type(8)));
typedef float f32x4  __attribute__((ext_vector_type(4)));

#define NB 64
#define NN 512
#define DD 128

// RNE float -> bf16 (finite inputs)
__device__ __forceinline__ unsigned short f2bf(float f) {
    unsigned int u = __float_as_uint(f);
    unsigned int r = (u + 0x7FFFu + ((u >> 16) & 1u)) >> 16;
    return (unsigned short)r;
}

// Kernel 1: per-row L2 normalize, write bf16 fn into workspace.
// 4 rows per wave (ILP across the 4 shuffle-reduce chains), 2048 blocks.
__global__ __launch_bounds__(256) void ASG_norm_kernel(
    const float* __restrict__ fea, unsigned int* __restrict__ fn)
{
    const int wid  = threadIdx.x >> 6;
    const int lane = threadIdx.x & 63;
    const int row0 = blockIdx.x * 16 + wid * 4;
    const float2* src = reinterpret_cast<const float2*>(fea);

    float2 v[4];
    float  s[4];
#pragma unroll
    for (int rr = 0; rr < 4; ++rr) {
        v[rr] = src[(size_t)(row0 + rr) * (DD / 2) + lane];
        s[rr] = v[rr].x * v[rr].x + v[rr].y * v[rr].y;
    }
#pragma unroll
    for (int o = 32; o; o >>= 1) {
#pragma unroll
        for (int rr = 0; rr < 4; ++rr) s[rr] += __shfl_xor(s[rr], o);
    }
#pragma unroll
    for (int rr = 0; rr < 4; ++rr) {
        const float scale = 1.0f / fmaxf(sqrtf(s[rr]), 1e-8f);
        const unsigned short a = f2bf(v[rr].x * scale);
        const unsigned short b = f2bf(v[rr].y * scale);
        fn[(size_t)(row0 + rr) * (DD / 2) + lane] =
            (unsigned int)a | ((unsigned int)b << 16);
    }
}

// Kernel 2: per (batch, 128x128 tile). 1-D grid with XCD-pinning decode:
// all 16 tiles of a batch land on one XCD so the batch's fn slice (131 KB)
// is fetched into that XCD's L2 exactly once.
__global__ __launch_bounds__(256) void ASG_adj_kernel(
    const unsigned short* __restrict__ fn, const float* __restrict__ coord,
    float* __restrict__ out)
{
    const int id  = blockIdx.x;        // 0..1023
    const int xcd = id & 7;            // dispatch round-robins blocks % 8 XCDs
    const int q   = id >> 3;           // 0..127
    const int b   = xcd + 8 * (q >> 4);
    const int t   = q & 15;
    const int bi  = t >> 2;            // row tile 0..3
    const int bj  = t & 3;             // col tile 0..3

    const int tid = threadIdx.x;
    const int wid = tid >> 6, lane = tid & 63;
    const int wr  = wid >> 1, wc = wid & 1;
    const int row0 = bi * 128 + wr * 64;
    const int col0 = bj * 128 + wc * 64;
    const int lo = lane & 15, hi = lane >> 4;

    __shared__ float2 crow[128];
    __shared__ float2 ccol[128];
    __shared__ float  xpose[4][16 * 68];   // per-wave transpose buffer (pad 68)

    const float2* cb = reinterpret_cast<const float2*>(coord) + (size_t)b * NN;
    if (tid < 128) crow[tid] = cb[bi * 128 + tid];
    else           ccol[tid - 128] = cb[bj * 128 + (tid - 128)];
    __syncthreads();

    const unsigned short* fb = fn + (size_t)b * NN * DD;
    const int lk = hi * 8;             // k start (bf16 elements)

    // B fragments: col = col0 + n*16 + lo, k = kk*32 + lk .. +8
    bf16x8 bfrag[4][4];
#pragma unroll
    for (int n = 0; n < 4; ++n) {
        const unsigned short* p = fb + (size_t)(col0 + n * 16 + lo) * DD + lk;
#pragma unroll
        for (int kk = 0; kk < 4; ++kk)
            bfrag[n][kk] = *reinterpret_cast<const bf16x8*>(p + kk * 32);
    }

    f32x4 acc[4][4];
#pragma unroll
    for (int m = 0; m < 4; ++m)
#pragma unroll
        for (int n = 0; n < 4; ++n)
            acc[m][n] = (f32x4){0.f, 0.f, 0.f, 0.f};

#pragma unroll
    for (int m = 0; m < 4; ++m) {
        const unsigned short* p = fb + (size_t)(row0 + m * 16 + lo) * DD + lk;
        bf16x8 afrag[4];
#pragma unroll
        for (int kk = 0; kk < 4; ++kk)
            afrag[kk] = *reinterpret_cast<const bf16x8*>(p + kk * 32);
#pragma unroll
        for (int n = 0; n < 4; ++n)
#pragma unroll
            for (int kk = 0; kk < 4; ++kk)
                acc[m][n] = __builtin_amdgcn_mfma_f32_16x16x32_bf16(
                    afrag[kk], bfrag[n][kk], acc[m][n], 0, 0, 0);
    }

    // Epilogue. MFMA C layout: local col = lo, local row = hi*4 + r.
    float* outA = out + (size_t)b * NN * NN;
    float* outS = out + (size_t)NB * NN * NN + (size_t)b * NN * NN;
    float* xp = xpose[wid];

    // this lane's 4 output columns (after transpose)
    const int jbase = col0 + lo * 4;
    float2 cj[4];
#pragma unroll
    for (int q2 = 0; q2 < 4; ++q2) cj[q2] = ccol[wc * 64 + lo * 4 + q2];

#pragma unroll
    for (int m = 0; m < 4; ++m) {
        // scatter acc[m][*] into LDS: [local_row][local_col], stride 68
#pragma unroll
        for (int n = 0; n < 4; ++n)
#pragma unroll
            for (int r = 0; r < 4; ++r)
                xp[(hi * 4 + r) * 68 + n * 16 + lo] = acc[m][n][r];
        // read back transposed: 4 rows x 64 cols per pass, dwordx4/lane
#pragma unroll
        for (int p = 0; p < 4; ++p) {
            const int rr = p * 4 + hi;                 // local row 0..15
            const f32x4 cv = *reinterpret_cast<const f32x4*>(&xp[rr * 68 + lo * 4]);
            const int i = row0 + m * 16 + rr;
            const float2 ci = crow[wr * 64 + m * 16 + rr];
            f32x4 av, sv;
#pragma unroll
            for (int q2 = 0; q2 < 4; ++q2) {
                const int j = jbase + q2;
                // bit-exact match to numpy: mul, mul, add, sqrt (no FMA)
                const float dx = ci.x - cj[q2].x;
                const float dy = ci.y - cj[q2].y;
                const float d2 = __fadd_rn(__fmul_rn(dx, dx), __fmul_rn(dy, dy));
                const float dist = __fsqrt_rn(d2);
                const bool diag = (i == j);
                av[q2] = diag ? 0.0f : cv[q2] * __expf(-dist);
                sv[q2] = (!diag && dist < 1.0f) ? 1.0f : 0.0f;
            }
            const size_t off = (size_t)i * NN + jbase;
            __builtin_nontemporal_store(av, reinterpret_cast<f32x4*>(outA + off));
            __builtin_nontemporal_store(sv, reinterpret_cast<f32x4*>(outS + off));
        }
    }
}

extern "C" void kernel_launch(void* const* d_in, const int* in_sizes, int n_in,
                              void* d_out, int out_size, void* d_ws, size_t ws_size,
                              hipStream_t stream) {
    const float* fea   = (const float*)d_in[0];   // [64,512,128] f32
    const float* coord = (const float*)d_in[1];   // [64,512,2]   f32
    float* out = (float*)d_out;                   // [2,64,512,512] f32
    unsigned int* fn_ws = (unsigned int*)d_ws;    // bf16 fn, 8 MB

    ASG_norm_kernel<<<dim3(NB * NN / 16), 256, 0, stream>>>(fea, fn_ws);
    ASG_adj_kernel<<<dim3(4 * 4 * NB), 256, 0, stream>>>(
        (const unsigned short*)fn_ws, coord, out);
}

// Round 4
// 41.767 us; speedup vs baseline: 1.2277x; 1.0648x over previous
//
#include <hip/hip_runtime.h>
#include <hip/hip_bf16.h>

typedef short bf16x8 __attribute__((ext_vector_type(8)));
typedef float f32x4  __attribute__((ext_vector_type(4)));

#define NB 64
#define NN 512
#define DD 128

// RNE float -> bf16 (finite inputs)
__device__ __forceinline__ unsigned short f2bf(float f) {
    unsigned int u = __float_as_uint(f);
    unsigned int r = (u + 0x7FFFu + ((u >> 16) & 1u)) >> 16;
    return (unsigned short)r;
}

// Kernel 1: per-row L2 normalize, write bf16 fn into workspace.
__global__ __launch_bounds__(256) void ASG_norm_kernel(
    const float* __restrict__ fea, unsigned int* __restrict__ fn)
{
    const int wid  = threadIdx.x >> 6;
    const int lane = threadIdx.x & 63;
    const int row0 = blockIdx.x * 16 + wid * 4;
    const float2* src = reinterpret_cast<const float2*>(fea);

    float2 v[4];
    float  s[4];
#pragma unroll
    for (int rr = 0; rr < 4; ++rr) {
        v[rr] = src[(size_t)(row0 + rr) * (DD / 2) + lane];
        s[rr] = v[rr].x * v[rr].x + v[rr].y * v[rr].y;
    }
#pragma unroll
    for (int o = 32; o; o >>= 1) {
#pragma unroll
        for (int rr = 0; rr < 4; ++rr) s[rr] += __shfl_xor(s[rr], o);
    }
#pragma unroll
    for (int rr = 0; rr < 4; ++rr) {
        const float scale = 1.0f / fmaxf(sqrtf(s[rr]), 1e-8f);
        const unsigned short a = f2bf(v[rr].x * scale);
        const unsigned short b = f2bf(v[rr].y * scale);
        fn[(size_t)(row0 + rr) * (DD / 2) + lane] =
            (unsigned int)a | ((unsigned int)b << 16);
    }
}

// Kernel 2: per (batch, 128x64 tile). 4 waves, each owns 64x32.
// Per-m interleave: 8 MFMAs then immediately epilogue+stores for that
// 16-row group, so waves alternate compute/store phases and desync.
__global__ __launch_bounds__(256, 4) void ASG_adj_kernel(
    const unsigned short* __restrict__ fn, const float* __restrict__ coord,
    float* __restrict__ out)
{
    const int id  = blockIdx.x;        // 0..2047
    const int xcd = id & 7;            // dispatch round-robins blocks % 8 XCDs
    const int q   = id >> 3;           // 0..255
    const int b   = xcd + 8 * (q >> 5);
    const int t   = q & 31;
    const int bi  = t >> 3;            // 128-row stripe 0..3
    const int bj  = t & 7;             // 64-col stripe 0..7

    const int tid = threadIdx.x;
    const int wid = tid >> 6, lane = tid & 63;
    const int wr  = wid >> 1, wc = wid & 1;
    const int row0 = bi * 128 + wr * 64;
    const int col0 = bj * 64  + wc * 32;
    const int lo = lane & 15, hi = lane >> 4;

    __shared__ float2 crow[128];
    __shared__ float2 ccol[64];
    __shared__ float  xpose[4][16 * 36];   // per-wave transpose buf (pad 36)

    const float2* cb = reinterpret_cast<const float2*>(coord) + (size_t)b * NN;
    if (tid < 128)      crow[tid] = cb[bi * 128 + tid];
    else if (tid < 192) ccol[tid - 128] = cb[bj * 64 + (tid - 128)];
    __syncthreads();

    const unsigned short* fb = fn + (size_t)b * NN * DD;
    const int lk = hi * 8;             // k start (bf16 elements)

    // B fragments: col = col0 + n*16 + lo
    bf16x8 bfrag[2][4];
#pragma unroll
    for (int n = 0; n < 2; ++n) {
        const unsigned short* p = fb + (size_t)(col0 + n * 16 + lo) * DD + lk;
#pragma unroll
        for (int kk = 0; kk < 4; ++kk)
            bfrag[n][kk] = *reinterpret_cast<const bf16x8*>(p + kk * 32);
    }

    float* outA = out + (size_t)b * NN * NN;
    float* outS = out + (size_t)NB * NN * NN + (size_t)b * NN * NN;
    float* xp = xpose[wid];

    // this lane's 4 output columns (after transpose): jbase..jbase+3
    const int c4 = (lane & 7) * 4;
    const int jbase = col0 + c4;
    float2 cj[4];
#pragma unroll
    for (int q2 = 0; q2 < 4; ++q2) cj[q2] = ccol[wc * 32 + c4 + q2];

#pragma unroll
    for (int m = 0; m < 4; ++m) {
        // A fragments for this 16-row group
        const unsigned short* p = fb + (size_t)(row0 + m * 16 + lo) * DD + lk;
        bf16x8 afrag[4];
#pragma unroll
        for (int kk = 0; kk < 4; ++kk)
            afrag[kk] = *reinterpret_cast<const bf16x8*>(p + kk * 32);

        f32x4 acc[2];
#pragma unroll
        for (int n = 0; n < 2; ++n) acc[n] = (f32x4){0.f, 0.f, 0.f, 0.f};
#pragma unroll
        for (int n = 0; n < 2; ++n)
#pragma unroll
            for (int kk = 0; kk < 4; ++kk)
                acc[n] = __builtin_amdgcn_mfma_f32_16x16x32_bf16(
                    afrag[kk], bfrag[n][kk], acc[n], 0, 0, 0);

        // scatter into LDS: [local_row][local_col], stride 36
#pragma unroll
        for (int n = 0; n < 2; ++n)
#pragma unroll
            for (int r = 0; r < 4; ++r)
                xp[(hi * 4 + r) * 36 + n * 16 + lo] = acc[n][r];

        // read back transposed: 8 rows x 32 cols per pass, dwordx4/lane
#pragma unroll
        for (int p2 = 0; p2 < 2; ++p2) {
            const int rr = p2 * 8 + (lane >> 3);       // local row 0..15
            const f32x4 cv = *reinterpret_cast<const f32x4*>(&xp[rr * 36 + c4]);
            const int i = row0 + m * 16 + rr;
            const float2 ci = crow[wr * 64 + m * 16 + rr];
            f32x4 av, sv;
#pragma unroll
            for (int q2 = 0; q2 < 4; ++q2) {
                const int j = jbase + q2;
                // bit-exact match to numpy: mul, mul, add, sqrt (no FMA)
                const float dx = ci.x - cj[q2].x;
                const float dy = ci.y - cj[q2].y;
                const float d2 = __fadd_rn(__fmul_rn(dx, dx), __fmul_rn(dy, dy));
                const float dist = __fsqrt_rn(d2);
                const bool diag = (i == j);
                av[q2] = diag ? 0.0f : cv[q2] * __expf(-dist);
                sv[q2] = (!diag && dist < 1.0f) ? 1.0f : 0.0f;
            }
            const size_t off = (size_t)i * NN + jbase;
            __builtin_nontemporal_store(av, reinterpret_cast<f32x4*>(outA + off));
            __builtin_nontemporal_store(sv, reinterpret_cast<f32x4*>(outS + off));
        }
    }
}

extern "C" void kernel_launch(void* const* d_in, const int* in_sizes, int n_in,
                              void* d_out, int out_size, void* d_ws, size_t ws_size,
                              hipStream_t stream) {
    const float* fea   = (const float*)d_in[0];   // [64,512,128] f32
    const float* coord = (const float*)d_in[1];   // [64,512,2]   f32
    float* out = (float*)d_out;                   // [2,64,512,512] f32
    unsigned int* fn_ws = (unsigned int*)d_ws;    // bf16 fn, 8 MB

    ASG_norm_kernel<<<dim3(NB * NN / 16), 256, 0, stream>>>(fea, fn_ws);
    ASG_adj_kernel<<<dim3(4 * 8 * NB), 256, 0, stream>>>(
        (const unsigned short*)fn_ws, coord, out);
}